// Round 1
// baseline (1077.389 us; speedup 1.0000x reference)
//
#include <hip/hip_runtime.h>

// ---------------------------------------------------------------------------
// Seq2Seq LSTM (enc 64 steps -> dec 63 steps -> FC to vocab), MI355X gfx950.
// Round 1: correctness-first structure.
//   k_pack_whh : Whh -> f16, packed-transposed [k8][row] (coalesced GEMV loads)
//   k_pack_wih : Wih -> f32, packed-transposed [e4][g]
//   k_pre      : embeddings + x@Wih^T + b for all 127 steps (parallel)
//   k_lstm     : 32 WGs (1 per batch elem), sync-free sequential recurrence,
//                f16 weights + v_dot2_f32_f16, h in LDS (f16), c in registers
//   k_zero0    : out[:,0,:] = 0
//   k_fc       : bf16 MFMA GEMM [2016x256]@[256x32000] + bias -> out[:,1:,:]
// Scratch: pre-activations + packed weights carved from d_out (dead before
// any output writes); d_ws holds decoder hidden states (8.3 MB).
// ---------------------------------------------------------------------------

typedef _Float16 f16x2 __attribute__((ext_vector_type(2)));
typedef short short8 __attribute__((ext_vector_type(8)));
typedef float f32x4 __attribute__((ext_vector_type(4)));

#define DEV __device__ __forceinline__

static constexpr int Vv = 32000, Ee = 128, Hh = 256, Bb = 32, Ss = 64, Tt = 64;
static constexpr int G4 = 4 * Hh;             // 1024 gate outputs
static constexpr int MR = (Tt - 1) * Bb;      // 2016 logit rows
static constexpr size_t OUT_BT = (size_t)Tt * Vv;  // per-batch out stride (2,048,000)

// scratch carved from d_out (bytes)
static constexpr size_t OFF_ENCPRE = 0;                                    // 64*32*1024 f32
static constexpr size_t OFF_DECPRE = OFF_ENCPRE + (size_t)Ss * Bb * G4 * 4;  // 8,388,608
static constexpr size_t OFF_WQE    = OFF_DECPRE + (size_t)(Tt - 1) * Bb * G4 * 4; // +8,257,536
static constexpr size_t OFF_WQD    = OFF_WQE + (size_t)G4 * Hh * 2;        // +524,288
static constexpr size_t OFF_WPE    = OFF_WQD + (size_t)G4 * Hh * 2;
static constexpr size_t OFF_WPD    = OFF_WPE + (size_t)G4 * Ee * 4;
// end = 18,743,296 bytes << 262,144,000-byte output buffer

DEV float sigm(float x) { return 1.0f / (1.0f + expf(-x)); }

DEV unsigned short f2bf(float x) {
  unsigned u = __float_as_uint(x);
  u = u + 0x7fffu + ((u >> 16) & 1u);   // RNE
  return (unsigned short)(u >> 16);
}

DEV float dot2(unsigned wu, unsigned hu, float acc) {
  union { unsigned u; f16x2 v; } a, b;
  a.u = wu; b.u = hu;
#if __has_builtin(__builtin_amdgcn_fdot2)
  return __builtin_amdgcn_fdot2(a.v, b.v, acc, false);
#else
  return acc + (float)a.v.x * (float)b.v.x + (float)a.v.y * (float)b.v.y;
#endif
}

// --- pack Whh [1024][256] f32 -> f16 layout: dst[((k>>3)*1024 + r)*8 + (k&7)]
__global__ __launch_bounds__(256) void k_pack_whh(const float* __restrict__ src,
                                                  _Float16* __restrict__ dst) {
  int tid = blockIdx.x * 256 + threadIdx.x;
  if (tid >= G4 * Hh) return;
  int r = tid >> 8, k = tid & 255;
  dst[((size_t)(k >> 3) * G4 + r) * 8 + (k & 7)] = (_Float16)src[tid];
}

// --- pack Wih [1024][128] f32 -> f32 layout: dst[((e>>2)*1024 + g)*4 + (e&3)]
__global__ __launch_bounds__(256) void k_pack_wih(const float* __restrict__ src,
                                                  float* __restrict__ dst) {
  int tid = blockIdx.x * 256 + threadIdx.x;
  if (tid >= G4 * Ee) return;
  int g = tid >> 7, e = tid & 127;
  dst[((size_t)(e >> 2) * G4 + g) * 4 + (e & 3)] = src[tid];
}

// --- pre[step][b][g] = emb[tok][.] @ Wih^T + b   (127 steps x 32 batch x 1024)
// grid: 127*4 blocks (4 batch-groups of 8), 1024 threads (one per gate col)
__global__ __launch_bounds__(1024) void k_pre(
    const int* __restrict__ src, const int* __restrict__ trg,
    const float* __restrict__ enc_emb, const float* __restrict__ dec_emb,
    const float* __restrict__ WpE, const float* __restrict__ WpD,
    const float* __restrict__ enc_b, const float* __restrict__ dec_b,
    float* __restrict__ enc_pre, float* __restrict__ dec_pre) {
  int blk = blockIdx.x;           // 0..507
  int step = blk >> 2;            // 0..126
  int b0 = (blk & 3) * 8;
  bool enc = step < Ss;
  int ts = enc ? step : step - Ss;            // enc s or dec t
  const int*   tok  = enc ? src : trg;
  const float* emb  = enc ? enc_emb : dec_emb;
  const float* Wp   = enc ? WpE : WpD;
  const float* bias = enc ? enc_b : dec_b;
  float* pre = enc ? (enc_pre + ((size_t)step * Bb + b0) * G4)
                   : (dec_pre + ((size_t)(step - Ss) * Bb + b0) * G4);

  __shared__ __align__(16) float xs[8][128];
  int tid = threadIdx.x;
  {
    int bl = tid >> 7, e = tid & 127;
    int token = tok[(b0 + bl) * 64 + ts];
    xs[bl][e] = emb[(size_t)token * Ee + e];
  }
  __syncthreads();

  int g = tid;
  float acc[8];
  float bv = bias[g];
#pragma unroll
  for (int bb = 0; bb < 8; ++bb) acc[bb] = bv;

  const f32x4* w4 = (const f32x4*)Wp;
  const f32x4(*x4)[32] = (const f32x4(*)[32])xs;
#pragma unroll 4
  for (int e4 = 0; e4 < 32; ++e4) {
    f32x4 w = w4[(size_t)e4 * G4 + g];
#pragma unroll
    for (int bb = 0; bb < 8; ++bb) {
      f32x4 xv = x4[bb][e4];
      acc[bb] += w.x * xv.x + w.y * xv.y + w.z * xv.z + w.w * xv.w;
    }
  }
#pragma unroll
  for (int bb = 0; bb < 8; ++bb) pre[(size_t)bb * G4 + g] = acc[bb];
}

// --- sequential recurrence: 1 WG per batch element, no inter-WG sync.
// 1024 threads: thread t computes gate element t (gate = t>>8, col = t&255).
__global__ __launch_bounds__(1024, 1) void k_lstm(
    const float* __restrict__ enc_pre, const float* __restrict__ dec_pre,
    const _Float16* __restrict__ WqE, const _Float16* __restrict__ WqD,
    float* __restrict__ hs) {
  int b = blockIdx.x;
  int t = threadIdx.x;
  __shared__ __align__(16) _Float16 harr[Hh];   // h as f16 (dot2 operand)
  __shared__ float gbuf[G4];
  float c = 0.0f;                               // cell state, thread t<256 owns c[t]
  if (t < Hh) harr[t] = (_Float16)0.0f;
  __syncthreads();

  const uint4* wE = (const uint4*)WqE;          // element (k8*1024 + row), 8 halves
  const uint4* wD = (const uint4*)WqD;
  const uint4* hv = (const uint4*)harr;         // 32 x (8 halves)

  for (int step = 0; step < 127; ++step) {
    bool enc = step < Ss;
    const float* pre = enc ? (enc_pre + ((size_t)step * Bb + b) * G4)
                           : (dec_pre + ((size_t)(step - Ss) * Bb + b) * G4);
    float acc = pre[t];
    const uint4* wrow = (enc ? wE : wD) + t;
#pragma unroll 8
    for (int k8 = 0; k8 < 32; ++k8) {
      uint4 w = wrow[(size_t)k8 * G4];          // coalesced: lanes at 16B stride
      uint4 h8 = hv[k8];                        // LDS broadcast
      acc = dot2(w.x, h8.x, acc);
      acc = dot2(w.y, h8.y, acc);
      acc = dot2(w.z, h8.z, acc);
      acc = dot2(w.w, h8.w, acc);
    }
    gbuf[t] = acc;
    __syncthreads();                            // all dots done (harr reads finished)
    if (t < Hh) {
      float gi = gbuf[t], gf = gbuf[Hh + t], gg = gbuf[2 * Hh + t], go = gbuf[3 * Hh + t];
      c = sigm(gf) * c + sigm(gi) * tanhf(gg);
      float hn = sigm(go) * tanhf(c);
      harr[t] = (_Float16)hn;
      if (!enc) hs[((size_t)(step - Ss) * Bb + b) * Hh + t] = hn;
    }
    __syncthreads();                            // h visible for next step
  }
}

// --- out[:,0,:] = 0
__global__ __launch_bounds__(256) void k_zero0(float* __restrict__ out) {
  int v = blockIdx.x * 256 + threadIdx.x;       // grid.x = 125 -> exactly 32000
  out[(size_t)blockIdx.y * OUT_BT + v] = 0.0f;
}

// --- FC: logits[row=t*32+b][v] = hs[row] . fc_W[v] + fc_b[v] -> out[b][t+1][v]
// 64x64 tile per WG, bf16 MFMA 16x16x32, K=256 staged in two 128-halves.
__global__ __launch_bounds__(256) void k_fc(const float* __restrict__ hs,
                                            const float* __restrict__ fcW,
                                            const float* __restrict__ fcb,
                                            float* __restrict__ out) {
  constexpr int LDH = 136;                      // +8 halves pad: 2-way conflicts only
  __shared__ __align__(16) unsigned short As[64 * LDH];
  __shared__ __align__(16) unsigned short Bs[64 * LDH];
  int n0 = blockIdx.x * 64, m0 = blockIdx.y * 64;
  int tid = threadIdx.x;
  int lane = tid & 63, wave = tid >> 6;
  int l15 = lane & 15, q = lane >> 4;
  int msub = (wave & 1) * 32, nsub = (wave >> 1) * 32;
  f32x4 acc[2][2] = {};

  for (int kb = 0; kb < 2; ++kb) {
#pragma unroll
    for (int r = 0; r < 4; ++r) {
      int vecid = tid + 256 * r;                // 0..1023
      int i = vecid >> 4;                       // row 0..63
      int kk = (vecid & 15) * 8;                // 0..120
      int gk = kb * 128 + kk;
      short8 va, vb;
      int gm = m0 + i;
      if (gm < MR) {
        const float* p = hs + (size_t)gm * Hh + gk;
#pragma unroll
        for (int e = 0; e < 8; ++e) va[e] = (short)f2bf(p[e]);
      } else {
#pragma unroll
        for (int e = 0; e < 8; ++e) va[e] = 0;
      }
      const float* pb = fcW + (size_t)(n0 + i) * Hh + gk;
#pragma unroll
      for (int e = 0; e < 8; ++e) vb[e] = (short)f2bf(pb[e]);
      *(short8*)&As[i * LDH + kk] = va;
      *(short8*)&Bs[i * LDH + kk] = vb;
    }
    __syncthreads();
#pragma unroll
    for (int ks = 0; ks < 4; ++ks) {
      int koff = ks * 32 + q * 8;
      short8 a0 = *(const short8*)&As[(msub + l15) * LDH + koff];
      short8 a1 = *(const short8*)&As[(msub + 16 + l15) * LDH + koff];
      short8 b0 = *(const short8*)&Bs[(nsub + l15) * LDH + koff];
      short8 b1 = *(const short8*)&Bs[(nsub + 16 + l15) * LDH + koff];
      acc[0][0] = __builtin_amdgcn_mfma_f32_16x16x32_bf16(a0, b0, acc[0][0], 0, 0, 0);
      acc[0][1] = __builtin_amdgcn_mfma_f32_16x16x32_bf16(a0, b1, acc[0][1], 0, 0, 0);
      acc[1][0] = __builtin_amdgcn_mfma_f32_16x16x32_bf16(a1, b0, acc[1][0], 0, 0, 0);
      acc[1][1] = __builtin_amdgcn_mfma_f32_16x16x32_bf16(a1, b1, acc[1][1], 0, 0, 0);
    }
    __syncthreads();
  }
  // epilogue: D[row=q*4+r][col=l15] per 16x16 sub-tile (m89-verified layout)
#pragma unroll
  for (int ni = 0; ni < 2; ++ni) {
    int gn = n0 + nsub + ni * 16 + l15;
    float bv = fcb[gn];
#pragma unroll
    for (int mi = 0; mi < 2; ++mi) {
#pragma unroll
      for (int r = 0; r < 4; ++r) {
        int gm = m0 + msub + mi * 16 + q * 4 + r;
        if (gm < MR) {
          int tt = gm >> 5, bb = gm & 31;
          out[(size_t)bb * OUT_BT + (size_t)(tt + 1) * Vv + gn] = acc[mi][ni][r] + bv;
        }
      }
    }
  }
}

extern "C" void kernel_launch(void* const* d_in, const int* in_sizes, int n_in,
                              void* d_out, int out_size, void* d_ws, size_t ws_size,
                              hipStream_t stream) {
  const int*   src     = (const int*)d_in[0];
  const int*   trg     = (const int*)d_in[1];
  const float* enc_emb = (const float*)d_in[2];
  const float* enc_Wih = (const float*)d_in[3];
  const float* enc_Whh = (const float*)d_in[4];
  const float* enc_b   = (const float*)d_in[5];
  const float* dec_emb = (const float*)d_in[6];
  const float* dec_Wih = (const float*)d_in[7];
  const float* dec_Whh = (const float*)d_in[8];
  const float* dec_b   = (const float*)d_in[9];
  const float* fc_W    = (const float*)d_in[10];
  const float* fc_b    = (const float*)d_in[11];
  float* out = (float*)d_out;

  // scratch carved from d_out (fully dead before k_zero0/k_fc write output)
  char* ob = (char*)d_out;
  float*     enc_pre = (float*)(ob + OFF_ENCPRE);
  float*     dec_pre = (float*)(ob + OFF_DECPRE);
  _Float16*  WqE     = (_Float16*)(ob + OFF_WQE);
  _Float16*  WqD     = (_Float16*)(ob + OFF_WQD);
  float*     WpE     = (float*)(ob + OFF_WPE);
  float*     WpD     = (float*)(ob + OFF_WPD);
  float*     hs      = (float*)d_ws;   // 63*32*256 f32 = 8,257,536 B

  k_pack_whh<<<1024, 256, 0, stream>>>(enc_Whh, WqE);
  k_pack_whh<<<1024, 256, 0, stream>>>(dec_Whh, WqD);
  k_pack_wih<<<512, 256, 0, stream>>>(enc_Wih, WpE);
  k_pack_wih<<<512, 256, 0, stream>>>(dec_Wih, WpD);
  k_pre<<<508, 1024, 0, stream>>>(src, trg, enc_emb, dec_emb, WpE, WpD,
                                  enc_b, dec_b, enc_pre, dec_pre);
  k_lstm<<<32, 1024, 0, stream>>>(enc_pre, dec_pre, WqE, WqD, hs);
  k_zero0<<<dim3(125, 32), 256, 0, stream>>>(out);
  k_fc<<<dim3(500, 32), 256, 0, stream>>>(hs, fc_W, fc_b, out);
}